// Round 9
// baseline (38.680 us; speedup 1.0000x reference)
//
#include <hip/hip_runtime.h>

#define HGT 1024
#define WID 1024
#define NB 8
#define NLAY 16
#define NPIX ((size_t)NB * HGT * WID)
#define ZBLKS 2048

// ---------------------------------------------------------------------------
// Node 1: fused zero-fill + interval reduce. Each thread: 4x {load T float4,
// load sos float4, store zero float4 to out} -> the compulsory 64 MB read and
// the compulsory 32 MB write overlap in one bidirectional stream. Per-block
// {maxT, minSos, bad} partials; no atomics. The zero pre-fill is always
// legal: node 2 either proves the true output rounds to +0 (keeps it) or
// overwrites with stencil results.
// ---------------------------------------------------------------------------
__global__ __launch_bounds__(256)
void zero_reduce(const float* __restrict__ T, const float* __restrict__ sos,
                 float* __restrict__ out, uint4* __restrict__ partials) {
    const float4* T4 = (const float4*)T;
    const float4* S4 = (const float4*)sos;
    float4* O4 = (float4*)out;
    const float4 z = make_float4(0.f, 0.f, 0.f, 0.f);
    float mT = 0.0f, mS = __builtin_huge_valf();
    unsigned bad = 0u;
    const size_t i0 = (size_t)blockIdx.x * 256 + threadIdx.x;
    #pragma unroll
    for (int k = 0; k < 4; ++k) {             // 2048 blk x 256 th x 4 == NPIX/4
        const size_t i = i0 + (size_t)k * (ZBLKS * 256);
        const float4 t = T4[i], s = S4[i];
        O4[i] = z;                            // overlap write with loads
        // !(x>=0) catches negatives AND NaN
        bad |= (!(t.x >= 0.f)) | (!(t.y >= 0.f)) | (!(t.z >= 0.f)) | (!(t.w >= 0.f));
        bad |= (!(s.x >= 0.f)) | (!(s.y >= 0.f)) | (!(s.z >= 0.f)) | (!(s.w >= 0.f));
        mT = fmaxf(mT, fmaxf(fmaxf(t.x, t.y), fmaxf(t.z, t.w)));
        mS = fminf(mS, fminf(fminf(s.x, s.y), fminf(s.z, s.w)));
    }
    if (!partials) return;
    __shared__ float sT[256], sS[256];
    __shared__ unsigned sB[256];
    const int tid = threadIdx.x;
    sT[tid] = mT; sS[tid] = mS; sB[tid] = bad;
    __syncthreads();
    for (int st = 128; st > 0; st >>= 1) {
        if (tid < st) {
            sT[tid] = fmaxf(sT[tid], sT[tid + st]);
            sS[tid] = fminf(sS[tid], sS[tid + st]);
            sB[tid] |= sB[tid + st];
        }
        __syncthreads();
    }
    if (tid == 0)
        partials[blockIdx.x] =
            make_uint4(__float_as_uint(sT[0]), __float_as_uint(sS[0]), sB[0], 0u);
}

// ---------------------------------------------------------------------------
// Node 2: every block folds the 2048 partials (32 KB, L2-broadcast-hot),
// evaluates the rigorous underflow bound for the FULL 16-layer chain:
//   T_out <= maxT * prod_l(sum_taps_l * maxSlow),  maxSlow = rn(1/minSos)
// (rn monotone => >= every per-elem rn(1/sos)). Log2-space; threshold -151
// vs fp32's -150 round-to-zero cutoff leaves ~1 bit for log2f error +
// ~210 op-rounding eps. NaN/negative data or taps disable the bound.
//  holds -> RETURN: out already holds the correct all-zero result (node 1).
//  fails -> per-tile screen (halo-16 96x96 influence region, round-7-
//           validated), then if still needed the 16-iteration fused LDS
//           stencil (halo=16 trapezoid => inner 64x64 exact; zero ring +
//           zero OOI cells reproduce SAME zero padding; T>=0,w>0 =>
//           min(0,..)=0 preserves OOI zeros; general path = round-1-
//           validated FMA chain; uniform-weight box-sum path as round 3)
//           overwrites this tile.
// Inter-dispatch ordering makes node-1 stores visible; no atomics;
// per-tile decisions are pure functions of the inputs -> deterministic.
// ---------------------------------------------------------------------------
__global__ __launch_bounds__(256)
void eik_all(const float* __restrict__ Tin, const float* __restrict__ sos,
             const float* __restrict__ wts, float* __restrict__ Tout,
             const uint4* __restrict__ partials) {
    constexpr int TILE = 64, HALO = 16, P = 96;   // P = TILE + 2*HALO
    constexpr int LSTR = 99, LROWS = 98;          // +1 zero ring each side
    constexpr int CW = 6, CH = 6;                 // 96/16

    __shared__ float lds[LROWS * LSTR];           // 38.8 KB (fallback only)
    __shared__ float swt[NLAY * 9];
    __shared__ float redT[4], redS[4];
    __shared__ unsigned redB[4];
    __shared__ unsigned decision;

    const int tid = threadIdx.x;

    // XCD-chunked swizzle (grid = 2048 = 8 XCDs x 256 tiles = one image each)
    const unsigned bphys = blockIdx.x;
    const unsigned Lt = (bphys & 7u) * 256u + (bphys >> 3u);
    const int bx = Lt & 15, by = (Lt >> 4) & 15, bz = Lt >> 8;
    const int gx0 = bx * TILE - HALO, gy0 = by * TILE - HALO;
    const size_t base = (size_t)bz * HGT * WID;

    if (tid < NLAY * 9) swt[tid] = wts[tid];      // parallel weight stage

    // ---- decision inputs: global fold of partials, or per-tile stream
    float mT = 0.0f, mS = __builtin_huge_valf();
    unsigned bad = 0u;
    if (partials) {
        #pragma unroll
        for (int k = 0; k < ZBLKS / 256; ++k) {
            const uint4 p = partials[tid + k * 256];
            mT = fmaxf(mT, __uint_as_float(p.x));
            mS = fminf(mS, __uint_as_float(p.y));
            bad |= p.z;
        }
    } else {
        // per-tile 96x96 influence-region screen (round-7-validated)
        for (int i = tid; i < P * (P / 4); i += 256) {
            const int r = i / (P / 4), q = i % (P / 4);
            const int gy = gy0 + r, gx = gx0 + 4 * q;   // gx0 16-aligned
            if (gy >= 0 && gy < HGT && gx >= 0 && gx < WID) {
                const size_t o = base + (size_t)gy * WID + gx;
                const float4 t = *reinterpret_cast<const float4*>(&Tin[o]);
                const float4 s = *reinterpret_cast<const float4*>(&sos[o]);
                bad |= (!(t.x >= 0.f)) | (!(t.y >= 0.f)) | (!(t.z >= 0.f)) | (!(t.w >= 0.f));
                bad |= (!(s.x >= 0.f)) | (!(s.y >= 0.f)) | (!(s.z >= 0.f)) | (!(s.w >= 0.f));
                mT = fmaxf(mT, fmaxf(fmaxf(t.x, t.y), fmaxf(t.z, t.w)));
                mS = fminf(mS, fminf(fminf(s.x, s.y), fminf(s.z, s.w)));
            }
        }
    }
    #pragma unroll
    for (int off = 32; off > 0; off >>= 1) {
        mT = fmaxf(mT, __shfl_down(mT, off, 64));
        mS = fminf(mS, __shfl_down(mS, off, 64));
        bad |= __shfl_down(bad, off, 64);
    }
    const int wv = tid >> 6;
    if ((tid & 63) == 0) { redT[wv] = mT; redS[wv] = mS; redB[wv] = bad; }
    __syncthreads();
    if (tid == 0) {
        const float fT = fmaxf(fmaxf(redT[0], redT[1]), fmaxf(redT[2], redT[3]));
        const float fS = fminf(fminf(redS[0], redS[1]), fminf(redS[2], redS[3]));
        const unsigned fB = redB[0] | redB[1] | redB[2] | redB[3];
        unsigned dec = 0u;
        if (fB == 0u) {
            const float maxSlow = 1.0f / fS;
            float lb = log2f(fT);
            bool ok = true;
            #pragma unroll 1
            for (int l = 0; l < NLAY; ++l) {
                float ssum = 0.0f;
                #pragma unroll
                for (int k = 0; k < 9; ++k) {
                    const float w = swt[l * 9 + k];
                    ok &= (w >= 0.0f);
                    ssum += w;
                }
                lb += log2f(ssum * maxSlow);
            }
            if (ok && lb < -151.0f) dec = 1u;
        }
        decision = dec;
    }
    __syncthreads();

    // bound holds: out already contains the correct zeros (node 1) -> done
    if (decision != 0u) return;

    // ---- fallback: full 16-layer fused stencil overwrites this tile
    for (int i = tid; i < LROWS * LSTR; i += 256) lds[i] = 0.0f;
    __syncthreads();
    unsigned nz = 0u;
    for (int i = tid; i < P * P; i += 256) {
        const int r = i / P, c = i % P;
        const int gy = gy0 + r, gx = gx0 + c;
        float v = 0.0f;
        if (gy >= 0 && gy < HGT && gx >= 0 && gx < WID)
            v = Tin[base + (size_t)gy * WID + gx];
        nz |= __float_as_uint(v);
        lds[(r + 1) * LSTR + (c + 1)] = v;
    }
    // all-zero tile is a fixed point for ANY weights; out pre-zeroed -> done
    if (__syncthreads_and(nz == 0u)) return;

    const int tx = tid & 15, ty = tid >> 4;
    const int R0 = ty * CH, C0 = tx * CW;
    float slow[CH][CW];
    #pragma unroll
    for (int r = 0; r < CH; ++r) {
        #pragma unroll
        for (int j = 0; j < CW; ++j) {
            const int gy = gy0 + R0 + r, gx = gx0 + C0 + j;
            float sv = 1.0f;
            if (gy >= 0 && gy < HGT && gx >= 0 && gx < WID)
                sv = sos[base + (size_t)gy * WID + gx];
            slow[r][j] = 1.0f / sv;   // same single-division rounding as reference
        }
    }
    __syncthreads();

    float nw[CH][CW];
    #pragma unroll 1
    for (int it = 0; it < NLAY; ++it) {
        const float w00 = swt[it * 9 + 0], w01 = swt[it * 9 + 1], w02 = swt[it * 9 + 2];
        const float w10 = swt[it * 9 + 3], w11 = swt[it * 9 + 4], w12 = swt[it * 9 + 5];
        const float w20 = swt[it * 9 + 6], w21 = swt[it * 9 + 7], w22 = swt[it * 9 + 8];

        const bool uni = (w00 == w01) & (w01 == w02) & (w02 == w10) &
                         (w10 == w11) & (w11 == w12) & (w12 == w20) &
                         (w20 == w21) & (w21 == w22);

        float a[CW + 2], bb[CW + 2], cc[CW + 2];
        #pragma unroll
        for (int k = 0; k < CW + 2; ++k) a[k] = lds[R0 * LSTR + C0 + k];
        #pragma unroll
        for (int k = 0; k < CW + 2; ++k) bb[k] = lds[(R0 + 1) * LSTR + C0 + k];

        if (uni) {
            const float wu = w00;
            #pragma unroll
            for (int r = 0; r < CH; ++r) {
                #pragma unroll
                for (int k = 0; k < CW + 2; ++k) cc[k] = lds[(R0 + r + 2) * LSTR + C0 + k];
                float cs[CW + 2];
                #pragma unroll
                for (int k = 0; k < CW + 2; ++k) cs[k] = a[k] + bb[k] + cc[k];
                #pragma unroll
                for (int j = 0; j < CW; ++j) {
                    const float s9 = cs[j] + cs[j + 1] + cs[j + 2];
                    nw[r][j] = fminf(bb[j + 1], s9 * wu * slow[r][j]);
                }
                #pragma unroll
                for (int k = 0; k < CW + 2; ++k) { a[k] = bb[k]; bb[k] = cc[k]; }
            }
        } else {
            // exact general path (round-1-identical FMA chain)
            #pragma unroll
            for (int r = 0; r < CH; ++r) {
                #pragma unroll
                for (int k = 0; k < CW + 2; ++k) cc[k] = lds[(R0 + r + 2) * LSTR + C0 + k];
                #pragma unroll
                for (int j = 0; j < CW; ++j) {
                    float acc = a[j] * w00 + a[j + 1] * w01 + a[j + 2] * w02
                              + bb[j] * w10 + bb[j + 1] * w11 + bb[j + 2] * w12
                              + cc[j] * w20 + cc[j + 1] * w21 + cc[j + 2] * w22;
                    nw[r][j] = fminf(bb[j + 1], acc * slow[r][j]);
                }
                #pragma unroll
                for (int k = 0; k < CW + 2; ++k) { a[k] = bb[k]; bb[k] = cc[k]; }
            }
        }
        __syncthreads();
        #pragma unroll
        for (int r = 0; r < CH; ++r)
            #pragma unroll
            for (int j = 0; j < CW; ++j)
                lds[(R0 + r + 1) * LSTR + C0 + j + 1] = nw[r][j];
        __syncthreads();
    }

    // write valid inner TILE x TILE (float4, always fully in-image)
    #pragma unroll
    for (int k = 0; k < 4; ++k) {
        const int i = tid + k * 256;
        const int r = i >> 4, q = i & 15;
        const int o = (HALO + r + 1) * LSTR + HALO + 4 * q + 1;
        float4 v;
        v.x = lds[o]; v.y = lds[o + 1]; v.z = lds[o + 2]; v.w = lds[o + 3];
        *reinterpret_cast<float4*>(
            &Tout[base + (size_t)(gy0 + HALO + r) * WID + (gx0 + HALO + 4 * q)]) = v;
    }
}

extern "C" void kernel_launch(void* const* d_in, const int* in_sizes, int n_in,
                              void* d_out, int out_size, void* d_ws, size_t ws_size,
                              hipStream_t stream) {
    const float* T_init = (const float*)d_in[0];
    const float* sos    = (const float*)d_in[1];
    const float* wts    = (const float*)d_in[2];
    float* out = (float*)d_out;

    uint4* partials = (ws_size >= ZBLKS * sizeof(uint4)) ? (uint4*)d_ws : nullptr;

    zero_reduce<<<dim3(ZBLKS), dim3(256), 0, stream>>>(T_init, sos, out, partials);
    eik_all<<<dim3(2048), dim3(256), 0, stream>>>(T_init, sos, wts, out, partials);
}

// Round 10
// 35.983 us; speedup vs baseline: 1.0750x; 1.0750x over previous
//
#include <hip/hip_runtime.h>

#define HGT 1024
#define WID 1024
#define NB 8
#define NLAY 16

// ---------------------------------------------------------------------------
// Single-dispatch 16-layer eikonal sweep (round-7 structure, fastest measured)
// with the zero pre-fill hoisted to overlap the reduce loads.
//
// Per 64x64 output tile (halo 16 -> 96x96 influence region):
//  phase 0: issue the tile's 64x64 zero stores (fire-and-forget; they overlap
//           the phase-A loads; superseded in-order by the fallback's stores
//           from the SAME threads if the stencil runs).
//  phase A: stream T/sos over the 96x96 region (float4), reduce
//           {maxT, minSos, bad(neg/NaN)} block-wide.
//  bound:   T_out <= maxT * prod_l(sum_taps_l * maxSlow), maxSlow=rn(1/minSos)
//           (rn monotone => >= every per-elem rn(1/sos)). Log2-space;
//           threshold -151 vs fp32's -150 round-to-zero cutoff leaves ~1 bit
//           for log2f error + ~210 op-rounding eps. All influence lies within
//           the 96x96 region (values radius <=16, slowness radius <=15).
//  holds -> return (zeros already stored; true results round to +0).
//  fails -> 16-iteration fused stencil in LDS (halo=16: 1 cell/iter stale
//           contamination => inner 64x64 exact; zero ring + zero OOI cells
//           reproduce SAME zero padding; T>=0, w>0 => min(0,..)=0 preserves
//           OOI zeros). General path = round-1-validated FMA chain; uniform-
//           weight box-sum path as in round 3. All-zero tile -> return
//           (zeros already stored; fixed point for ANY weights).
//
// XCD swizzle: physical block b -> logical tile (b&7)*256 + (b>>3), so each
// XCD owns one batch image; halo re-reads hit that XCD's L2.
// No workspace, no atomics, deterministic (per-tile decisions are pure
// functions of tile data).
// ---------------------------------------------------------------------------
__global__ __launch_bounds__(256)
void eik_all(const float* __restrict__ Tin, const float* __restrict__ sos,
             const float* __restrict__ wts, float* __restrict__ Tout) {
    constexpr int TILE = 64, HALO = 16, P = 96;   // P = TILE + 2*HALO
    constexpr int LSTR = 99, LROWS = 98;          // +1 zero ring each side
    constexpr int CW = 6, CH = 6;                 // 96/16

    __shared__ float lds[LROWS * LSTR];           // 38.8 KB (fallback only)
    __shared__ float swt[NLAY * 9];
    __shared__ float redT[4], redS[4];
    __shared__ unsigned redB[4];
    __shared__ unsigned decision;

    const int tid = threadIdx.x;

    // XCD-chunked swizzle (grid = 2048 = 8 XCDs x 256 tiles = one image each)
    const unsigned bphys = blockIdx.x;
    const unsigned Lt = (bphys & 7u) * 256u + (bphys >> 3u);
    const int bx = Lt & 15, by = (Lt >> 4) & 15, bz = Lt >> 8;
    const int gx0 = bx * TILE - HALO, gy0 = by * TILE - HALO;
    const size_t base = (size_t)bz * HGT * WID;

    // ---- phase 0: zero pre-fill of this tile's 64x64 output (overlaps loads)
    #pragma unroll
    for (int k = 0; k < 4; ++k) {
        const int i = tid + k * 256;              // 1024 float4s
        const int r = i >> 4, q = i & 15;
        *reinterpret_cast<float4*>(
            &Tout[base + (size_t)(gy0 + HALO + r) * WID + (gx0 + HALO + 4 * q)]) =
            make_float4(0.f, 0.f, 0.f, 0.f);
    }

    if (tid < NLAY * 9) swt[tid] = wts[tid];      // parallel weight stage

    // ---- phase A: stream + reduce (no LDS staging; fallback re-reads L2-hot)
    float mT = 0.0f, mS = __builtin_huge_valf();
    unsigned bad = 0u;
    for (int i = tid; i < P * (P / 4); i += 256) {    // 2304 float4 pairs
        const int r = i / (P / 4), q = i % (P / 4);
        const int gy = gy0 + r, gx = gx0 + 4 * q;     // gx0 16-aligned: no straddle
        if (gy >= 0 && gy < HGT && gx >= 0 && gx < WID) {
            const size_t o = base + (size_t)gy * WID + gx;
            const float4 t = *reinterpret_cast<const float4*>(&Tin[o]);
            const float4 s = *reinterpret_cast<const float4*>(&sos[o]);
            // !(x>=0) catches negatives AND NaN
            bad |= (!(t.x >= 0.f)) | (!(t.y >= 0.f)) | (!(t.z >= 0.f)) | (!(t.w >= 0.f));
            bad |= (!(s.x >= 0.f)) | (!(s.y >= 0.f)) | (!(s.z >= 0.f)) | (!(s.w >= 0.f));
            mT = fmaxf(mT, fmaxf(fmaxf(t.x, t.y), fmaxf(t.z, t.w)));
            mS = fminf(mS, fminf(fminf(s.x, s.y), fminf(s.z, s.w)));
        }
    }
    #pragma unroll
    for (int off = 32; off > 0; off >>= 1) {
        mT = fmaxf(mT, __shfl_down(mT, off, 64));
        mS = fminf(mS, __shfl_down(mS, off, 64));
        bad |= __shfl_down(bad, off, 64);
    }
    const int wv = tid >> 6;
    if ((tid & 63) == 0) { redT[wv] = mT; redS[wv] = mS; redB[wv] = bad; }
    __syncthreads();
    if (tid == 0) {
        const float fT = fmaxf(fmaxf(redT[0], redT[1]), fmaxf(redT[2], redT[3]));
        const float fS = fminf(fminf(redS[0], redS[1]), fminf(redS[2], redS[3]));
        const unsigned fB = redB[0] | redB[1] | redB[2] | redB[3];
        unsigned dec = 0u;
        if (fB == 0u) {
            const float maxSlow = 1.0f / fS;
            float lb = log2f(fT);
            bool ok = true;
            #pragma unroll 1
            for (int l = 0; l < NLAY; ++l) {
                float ssum = 0.0f;
                #pragma unroll
                for (int k = 0; k < 9; ++k) {
                    const float w = swt[l * 9 + k];
                    ok &= (w >= 0.0f);
                    ssum += w;
                }
                lb += log2f(ssum * maxSlow);
            }
            if (ok && lb < -151.0f) dec = 1u;
        }
        decision = dec;
    }
    __syncthreads();

    // bound holds: zeros already stored (phase 0) -> done
    if (decision != 0u) return;

    // ---- fallback: full 16-layer fused stencil (tile data is L2-hot)
    for (int i = tid; i < LROWS * LSTR; i += 256) lds[i] = 0.0f;
    __syncthreads();
    unsigned nz = 0u;
    for (int i = tid; i < P * P; i += 256) {
        const int r = i / P, c = i % P;
        const int gy = gy0 + r, gx = gx0 + c;
        float v = 0.0f;
        if (gy >= 0 && gy < HGT && gx >= 0 && gx < WID)
            v = Tin[base + (size_t)gy * WID + gx];
        nz |= __float_as_uint(v);
        lds[(r + 1) * LSTR + (c + 1)] = v;
    }
    // all-zero tile: fixed point for ANY weights; zeros already stored -> done
    if (__syncthreads_and(nz == 0u)) return;

    const int tx = tid & 15, ty = tid >> 4;
    const int R0 = ty * CH, C0 = tx * CW;
    float slow[CH][CW];
    #pragma unroll
    for (int r = 0; r < CH; ++r) {
        #pragma unroll
        for (int j = 0; j < CW; ++j) {
            const int gy = gy0 + R0 + r, gx = gx0 + C0 + j;
            float sv = 1.0f;
            if (gy >= 0 && gy < HGT && gx >= 0 && gx < WID)
                sv = sos[base + (size_t)gy * WID + gx];
            slow[r][j] = 1.0f / sv;   // same single-division rounding as reference
        }
    }
    __syncthreads();

    float nw[CH][CW];
    #pragma unroll 1
    for (int it = 0; it < NLAY; ++it) {
        const float w00 = swt[it * 9 + 0], w01 = swt[it * 9 + 1], w02 = swt[it * 9 + 2];
        const float w10 = swt[it * 9 + 3], w11 = swt[it * 9 + 4], w12 = swt[it * 9 + 5];
        const float w20 = swt[it * 9 + 6], w21 = swt[it * 9 + 7], w22 = swt[it * 9 + 8];

        const bool uni = (w00 == w01) & (w01 == w02) & (w02 == w10) &
                         (w10 == w11) & (w11 == w12) & (w12 == w20) &
                         (w20 == w21) & (w21 == w22);

        float a[CW + 2], bb[CW + 2], cc[CW + 2];
        #pragma unroll
        for (int k = 0; k < CW + 2; ++k) a[k] = lds[R0 * LSTR + C0 + k];
        #pragma unroll
        for (int k = 0; k < CW + 2; ++k) bb[k] = lds[(R0 + 1) * LSTR + C0 + k];

        if (uni) {
            const float wu = w00;
            #pragma unroll
            for (int r = 0; r < CH; ++r) {
                #pragma unroll
                for (int k = 0; k < CW + 2; ++k) cc[k] = lds[(R0 + r + 2) * LSTR + C0 + k];
                float cs[CW + 2];
                #pragma unroll
                for (int k = 0; k < CW + 2; ++k) cs[k] = a[k] + bb[k] + cc[k];
                #pragma unroll
                for (int j = 0; j < CW; ++j) {
                    const float s9 = cs[j] + cs[j + 1] + cs[j + 2];
                    nw[r][j] = fminf(bb[j + 1], s9 * wu * slow[r][j]);
                }
                #pragma unroll
                for (int k = 0; k < CW + 2; ++k) { a[k] = bb[k]; bb[k] = cc[k]; }
            }
        } else {
            // exact general path (round-1-identical FMA chain)
            #pragma unroll
            for (int r = 0; r < CH; ++r) {
                #pragma unroll
                for (int k = 0; k < CW + 2; ++k) cc[k] = lds[(R0 + r + 2) * LSTR + C0 + k];
                #pragma unroll
                for (int j = 0; j < CW; ++j) {
                    float acc = a[j] * w00 + a[j + 1] * w01 + a[j + 2] * w02
                              + bb[j] * w10 + bb[j + 1] * w11 + bb[j + 2] * w12
                              + cc[j] * w20 + cc[j + 1] * w21 + cc[j + 2] * w22;
                    nw[r][j] = fminf(bb[j + 1], acc * slow[r][j]);
                }
                #pragma unroll
                for (int k = 0; k < CW + 2; ++k) { a[k] = bb[k]; bb[k] = cc[k]; }
            }
        }
        __syncthreads();
        #pragma unroll
        for (int r = 0; r < CH; ++r)
            #pragma unroll
            for (int j = 0; j < CW; ++j)
                lds[(R0 + r + 1) * LSTR + C0 + j + 1] = nw[r][j];
        __syncthreads();
    }

    // write valid inner TILE x TILE (float4; same thread->address mapping as
    // phase 0, so the stencil result supersedes the pre-fill in program order)
    #pragma unroll
    for (int k = 0; k < 4; ++k) {
        const int i = tid + k * 256;
        const int r = i >> 4, q = i & 15;
        const int o = (HALO + r + 1) * LSTR + HALO + 4 * q + 1;
        float4 v;
        v.x = lds[o]; v.y = lds[o + 1]; v.z = lds[o + 2]; v.w = lds[o + 3];
        *reinterpret_cast<float4*>(
            &Tout[base + (size_t)(gy0 + HALO + r) * WID + (gx0 + HALO + 4 * q)]) = v;
    }
}

extern "C" void kernel_launch(void* const* d_in, const int* in_sizes, int n_in,
                              void* d_out, int out_size, void* d_ws, size_t ws_size,
                              hipStream_t stream) {
    const float* T_init = (const float*)d_in[0];
    const float* sos    = (const float*)d_in[1];
    const float* wts    = (const float*)d_in[2];
    float* out = (float*)d_out;

    eik_all<<<dim3(2048), dim3(256), 0, stream>>>(T_init, sos, wts, out);
}